// Round 13
// baseline (370.664 us; speedup 1.0000x reference)
//
#include <hip/hip_runtime.h>
#include <hip/hip_bf16.h>
#include <stdint.h>

#define SEQ_LEN 3120
#define DIM 1536
#define QKV_N 4608
#define HEADS 12
#define HEAD_DIM 128
#define FRAME_LEN 1560
#define SM_SCALE 0.08838834764831845f   // 1/sqrt(128)
#define LOG2E 1.4426950408889634f
#define FMAXC2 43.280851226669165f      // 30*log2e; p = 2^(s' - 43.28)
#define BQ 256

#if __has_builtin(__builtin_amdgcn_exp2f)
#define FEXP2(x) __builtin_amdgcn_exp2f(x)
#else
#define FEXP2(x) exp2f(x)
#endif

typedef short short8 __attribute__((ext_vector_type(8)));
typedef float f32x4 __attribute__((ext_vector_type(4)));
typedef float f32x16 __attribute__((ext_vector_type(16)));

__device__ __forceinline__ unsigned short f2bf(float x) {
    union { float f; unsigned u; } v; v.f = x;
    unsigned r = v.u + 0x7fffu + ((v.u >> 16) & 1u);
    return (unsigned short)(r >> 16);
}
__device__ __forceinline__ float bf2f(unsigned short b) {
    union { unsigned u; float f; } v; v.u = ((unsigned)b) << 16;
    return v.f;
}
__device__ __forceinline__ unsigned pk2bf(float a, float b) {
    __hip_bfloat162 h = __float22bfloat162_rn(make_float2(a, b));
    union { __hip_bfloat162 h2; unsigned u; } v; v.h2 = h;
    return v.u;
}

__device__ __forceinline__ void async16(void* lds, const void* g) {
    __builtin_amdgcn_global_load_lds(
        (const __attribute__((address_space(1))) unsigned int*)g,
        (__attribute__((address_space(3))) unsigned int*)lds, 16, 0, 0);
}

// ---------------------------------------------------------------------------
// Fused prep: hs->bf16 convert (0..2339), w_qkv transpose (2340..4067),
// w_out transpose (4068..4643).
// ---------------------------------------------------------------------------
__device__ __forceinline__ void transpose_tile(
    const float* __restrict__ in, unsigned short* __restrict__ out,
    int R, int C, int c0, int r0, float (*T)[65], int tid)
{
    const int rl = tid >> 4, cl = (tid & 15) * 4;
#pragma unroll
    for (int i = 0; i < 4; ++i) {
        const int row = r0 + rl + i * 16;
        float4 v = *(const float4*)&in[(size_t)row * C + c0 + cl];
        T[cl + 0][rl + i * 16] = v.x; T[cl + 1][rl + i * 16] = v.y;
        T[cl + 2][rl + i * 16] = v.z; T[cl + 3][rl + i * 16] = v.w;
    }
    __syncthreads();
    const int oc = tid >> 2, ob = (tid & 3) * 16;
    union { unsigned short t[16]; uint4 u[2]; } p;
#pragma unroll
    for (int j = 0; j < 16; ++j) p.t[j] = f2bf(T[oc][ob + j]);
    uint4* dst = (uint4*)&out[(size_t)(c0 + oc) * R + r0 + ob];
    dst[0] = p.u[0];
    dst[1] = p.u[1];
}

__global__ __launch_bounds__(256) void prep_kernel(
    const float* __restrict__ hs, unsigned short* __restrict__ hsb,
    const float* __restrict__ w_qkv, unsigned short* __restrict__ wqkvT,
    const float* __restrict__ w_out, unsigned short* __restrict__ woutT)
{
    __shared__ float T[64][65];
    const int bid = blockIdx.x;
    const int tid = threadIdx.x;
    if (bid < 2340) {
        const int i = bid * 256 + tid;
        const float4 a = ((const float4*)hs)[i * 2];
        const float4 b = ((const float4*)hs)[i * 2 + 1];
        union { unsigned short t[8]; uint4 u; } p;
        p.t[0] = f2bf(a.x); p.t[1] = f2bf(a.y); p.t[2] = f2bf(a.z); p.t[3] = f2bf(a.w);
        p.t[4] = f2bf(b.x); p.t[5] = f2bf(b.y); p.t[6] = f2bf(b.z); p.t[7] = f2bf(b.w);
        ((uint4*)hsb)[i] = p.u;
    } else if (bid < 4068) {
        const int t = bid - 2340; // 72 x 24 tiles of w_qkv [1536][4608]
        transpose_tile(w_qkv, wqkvT, DIM, QKV_N, (t % 72) * 64, (t / 72) * 64, T, tid);
    } else {
        const int t = bid - 4068; // 24 x 24 tiles of w_out [1536][1536]
        transpose_tile(w_out, woutT, DIM, DIM, (t % 24) * 64, (t / 24) * 64, T, tid);
    }
}

// ---------------------------------------------------------------------------
// GEMM tile body (m97 structure), shared by both output dtypes.
// ---------------------------------------------------------------------------
#define GEMM_BODY(STORE_STMT)                                                   \
    f32x4 acc[4][4];                                                            \
    _Pragma("unroll")                                                           \
    for (int i = 0; i < 4; ++i)                                                 \
        _Pragma("unroll")                                                       \
        for (int j = 0; j < 4; ++j) acc[i][j] = f32x4{0.f, 0.f, 0.f, 0.f};      \
    const int c0i = (w * 2) * 64 + l, c1i = c0i + 64;                           \
    const unsigned short* gA0 = A + (size_t)min(m0 + (c0i >> 2), M - 1) * K + (c0i & 3) * 8; \
    const unsigned short* gA1 = A + (size_t)min(m0 + (c1i >> 2), M - 1) * K + (c1i & 3) * 8; \
    const unsigned short* gB0 = Bt + (size_t)(n0 + (c0i >> 2)) * K + (c0i & 3) * 8; \
    const unsigned short* gB1 = Bt + (size_t)(n0 + (c1i >> 2)) * K + (c1i & 3) * 8; \
    short* lA0 = As + (w * 2 + 0) * 512;                                        \
    short* lA1 = As + (w * 2 + 1) * 512;                                        \
    short* lB0 = Bs + (w * 2 + 0) * 512;                                        \
    short* lB1 = Bs + (w * 2 + 1) * 512;                                        \
    const int aoff = (wr * 64 + llo) * 32 + lhi * 8;                            \
    const int boff = (wc * 64 + llo) * 32 + lhi * 8;                            \
    for (int k0 = 0; k0 < K; k0 += 32) {                                        \
        async16(lA0, gA0 + k0); async16(lA1, gA1 + k0);                         \
        async16(lB0, gB0 + k0); async16(lB1, gB1 + k0);                         \
        __syncthreads();                                                        \
        short8 af[4], bf[4];                                                    \
        _Pragma("unroll")                                                       \
        for (int mt = 0; mt < 4; ++mt) af[mt] = *(const short8*)&As[aoff + mt * 512]; \
        _Pragma("unroll")                                                       \
        for (int nt = 0; nt < 4; ++nt) bf[nt] = *(const short8*)&Bs[boff + nt * 512]; \
        _Pragma("unroll")                                                       \
        for (int mt = 0; mt < 4; ++mt)                                          \
            _Pragma("unroll")                                                   \
            for (int nt = 0; nt < 4; ++nt)                                      \
                acc[mt][nt] = __builtin_amdgcn_mfma_f32_16x16x32_bf16(af[mt], bf[nt], acc[mt][nt], 0, 0, 0); \
        __syncthreads();                                                        \
    }                                                                           \
    _Pragma("unroll")                                                           \
    for (int mt = 0; mt < 4; ++mt)                                              \
        _Pragma("unroll")                                                       \
        for (int ri = 0; ri < 4; ++ri) {                                        \
            const int row = m0 + wr * 64 + mt * 16 + lhi * 4 + ri;              \
            if (row < M) {                                                      \
                _Pragma("unroll")                                               \
                for (int nt = 0; nt < 4; ++nt) {                                \
                    const int col = n0 + wc * 64 + nt * 16 + llo;               \
                    STORE_STMT;                                                 \
                }                                                               \
            }                                                                   \
        }

// ---------------------------------------------------------------------------
// qkv GEMM, bf16 out — persistent 2-tile blocks, XCD-pair swizzled.
// Grid 456 = 8 x 57 (<=512 resident): single uniform round, no ragged tail.
// Pair (xcd>>1) owns 9 contiguous n-tiles; block does tiles 2*idx, 2*idx+1
// (consecutive -> usually same m: A-tile L2 reuse).
// ---------------------------------------------------------------------------
__global__ __launch_bounds__(256, 2) void gemm_qkv_kernel(
    const unsigned short* __restrict__ A, const unsigned short* __restrict__ Bt,
    const float* __restrict__ bias, unsigned short* __restrict__ C)
{
    __shared__ short As[128 * 32];
    __shared__ short Bs[128 * 32];
    const int M = SEQ_LEN, N = QKV_N, K = DIM;

    const int xcd = blockIdx.x & 7;
    const int pair = xcd >> 1;
    const int idx = (xcd & 1) * 57 + (blockIdx.x >> 3); // 0..113

    const int tid = threadIdx.x;
    const int w = tid >> 6, l = tid & 63;
    const int wr = w >> 1, wc = w & 1;
    const int lhi = l >> 4, llo = l & 15;

#pragma unroll 1
    for (int rep = 0; rep < 2; ++rep) {
        const int t = idx * 2 + rep;
        if (t >= 225) break; // 25 m-tiles x 9 n-tiles per pair
        const int m0 = (t / 9) * 128;
        const int n0 = (pair * 9 + t % 9) * 128;
        GEMM_BODY(C[(size_t)row * N + col] = f2bf(acc[mt][nt][ri] + bias[col]))
        __syncthreads(); // LDS reuse across reps
    }
}

// ---------------------------------------------------------------------------
// out GEMM, fp32 out, XCD-pair swizzled (single round already: 304 blocks).
// ---------------------------------------------------------------------------
__global__ __launch_bounds__(256, 2) void gemm_out_kernel(
    const unsigned short* __restrict__ A, const unsigned short* __restrict__ Bt,
    const float* __restrict__ bias, float* __restrict__ C)
{
    __shared__ short As[128 * 32];
    __shared__ short Bs[128 * 32];
    const int M = SEQ_LEN, N = DIM, K = DIM;

    const int xcd = blockIdx.x & 7;
    const int idx = (xcd & 1) * 38 + (blockIdx.x >> 3);
    if (idx >= 75) return; // 25 m x 3 n per pair
    const int m0 = (idx / 3) * 128;
    const int n0 = ((xcd >> 1) * 3 + idx % 3) * 128;

    const int tid = threadIdx.x;
    const int w = tid >> 6, l = tid & 63;
    const int wr = w >> 1, wc = w & 1;
    const int lhi = l >> 4, llo = l & 15;

    GEMM_BODY(C[(size_t)row * N + col] = acc[mt][nt][ri] + bias[col])
}

// ---------------------------------------------------------------------------
// Fused norm+vtrans launch: blocks 0..3119 do RMSNorm(q,k)+RoPE for one seq
// position; blocks 3120..3707 do V transpose (64 seq x 1 head each) with
// COALESCED writes (8 lanes x 8 consecutive s per od-row -> 128B segments).
// ---------------------------------------------------------------------------
__global__ __launch_bounds__(256) void normv_kernel(
    const unsigned short* __restrict__ qkvb, const float* __restrict__ gq,
    const float* __restrict__ gk, const float* __restrict__ cosf,
    const float* __restrict__ sinf, unsigned short* __restrict__ qb,
    unsigned short* __restrict__ kb, unsigned short* __restrict__ vt)
{
    __shared__ float T[128][65]; // vtrans staging (rms path uses tiny slice)
    const int bid = blockIdx.x;
    const int tid = threadIdx.x;

    if (bid < SEQ_LEN) {
        // ---- RMSNorm + RoPE ----
        const int s = bid;
        const unsigned short* qrow = qkvb + (size_t)s * QKV_N;
        const unsigned short* krow = qrow + DIM;

        float2 qp[3], kp[3];
        float ssq_q = 0.f, ssq_k = 0.f;
#pragma unroll
        for (int j = 0; j < 3; ++j) {
            const int p = tid + j * 256;
            const unsigned uq = *(const unsigned*)(qrow + 2 * p);
            const unsigned uk = *(const unsigned*)(krow + 2 * p);
            qp[j] = make_float2(bf2f((unsigned short)(uq & 0xffff)), bf2f((unsigned short)(uq >> 16)));
            kp[j] = make_float2(bf2f((unsigned short)(uk & 0xffff)), bf2f((unsigned short)(uk >> 16)));
            ssq_q += qp[j].x * qp[j].x + qp[j].y * qp[j].y;
            ssq_k += kp[j].x * kp[j].x + kp[j].y * kp[j].y;
        }
#pragma unroll
        for (int off = 32; off > 0; off >>= 1) {
            ssq_q += __shfl_down(ssq_q, off);
            ssq_k += __shfl_down(ssq_k, off);
        }
        const int wave = tid >> 6, lane = tid & 63;
        if (lane == 0) { T[0][wave] = ssq_q; T[1][wave] = ssq_k; }
        __syncthreads();
        const float tq = T[0][0] + T[0][1] + T[0][2] + T[0][3];
        const float tk = T[1][0] + T[1][1] + T[1][2] + T[1][3];
        const float inv_q = rsqrtf(tq * (1.0f / DIM) + 1e-6f) * (SM_SCALE * LOG2E);
        const float inv_k = rsqrtf(tk * (1.0f / DIM) + 1e-6f);

#pragma unroll
        for (int j = 0; j < 3; ++j) {
            const int p = tid + j * 256;
            const int fi = p & 63;
            const float c = cosf[s * 64 + fi];
            const float si = sinf[s * 64 + fi];
            {
                const float y1 = qp[j].x * inv_q * gq[2 * p];
                const float y2 = qp[j].y * inv_q * gq[2 * p + 1];
                *(unsigned*)&qb[(size_t)s * DIM + 2 * p] = pk2bf(y1 * c - y2 * si, y1 * si + y2 * c);
            }
            {
                const float y1 = kp[j].x * inv_k * gk[2 * p];
                const float y2 = kp[j].y * inv_k * gk[2 * p + 1];
                *(unsigned*)&kb[(size_t)s * DIM + 2 * p] = pk2bf(y1 * c - y2 * si, y1 * si + y2 * c);
            }
        }
    } else {
        // ---- V transpose, coalesced writes ----
        const int t = bid - SEQ_LEN;       // 0..587
        const int s0 = (t % 49) * 64;
        const int h = t / 49;
        const int rl = tid >> 2, cb = (tid & 3) * 32;
        const int row = min(s0 + rl, SEQ_LEN - 1);
#pragma unroll
        for (int i = 0; i < 4; ++i) {
            const int d = cb + i * 8;
            union { uint4 u; unsigned short tt[8]; } v;
            v.u = *(const uint4*)&qkvb[(size_t)row * QKV_N + 2 * DIM + h * HEAD_DIM + d];
#pragma unroll
            for (int j = 0; j < 8; ++j) T[d + j][rl] = bf2f(v.tt[j]);
        }
        __syncthreads();
        // 256 thr = 32 od-rows x 8 lanes; each lane packs 8 consecutive s.
        const int odb = tid >> 3;          // 0..31
        const int sg = (tid & 7) * 8;      // 0..56
        const int s = s0 + sg;
#pragma unroll
        for (int i = 0; i < 4; ++i) {
            const int od = odb + i * 32;
            if (s < SEQ_LEN) { // SEQ%8==0: 8-chunk fully valid or fully not
                union { unsigned short tt[8]; uint4 u; } pk;
#pragma unroll
                for (int j = 0; j < 8; ++j) pk.tt[j] = f2bf(T[od][sg + j]);
                *(uint4*)&vt[(size_t)(h * HEAD_DIM + od) * SEQ_LEN + s] = pk.u;
            }
        }
    }
}

// ---------------------------------------------------------------------------
// Flash attention pass 1 — r12 structure, unchanged (frozen: six variants
// converged to ~140us; counters stable; next lever needs disasm evidence).
// ---------------------------------------------------------------------------
__global__ __launch_bounds__(512) void attn_part_kernel(
    const unsigned short* __restrict__ qb, const unsigned short* __restrict__ kb,
    const unsigned short* __restrict__ vt, unsigned short* __restrict__ part_o,
    float* __restrict__ part_ml)
{
    __shared__ short KV[32768]; // 64KB double buffer

    const int bid = blockIdx.x;
    const int xcd = bid & 7;
    const int slot = bid >> 3;   // 0..59
    int h, bx;
    if (slot < 40) { h = xcd; bx = slot; }
    else { h = 8 + (xcd >> 1); bx = (xcd & 1) * 20 + (slot - 40); }

    const int tid = threadIdx.x;
    const int w = tid >> 6;
    const int l = tid & 63;
    int tile, split, nsp;
    if (bx < 12) { tile = bx >> 1; split = bx & 1; nsp = 2; }
    else { const int b2 = bx - 12; tile = 6 + (b2 >> 2); split = b2 & 3; nsp = 4; }
    const int q0 = tile * BQ;
    const int lhi = l >> 5;
    const int llo = l & 31;

#pragma unroll
    for (int s = 0; s < 8; ++s) {
        const int c = (s * 8 + w) * 64 + l;
        const int row = c >> 4, g = c & 15;
        const int gr = min(q0 + row, SEQ_LEN - 1);
        async16(KV + (s * 8 + w) * 512, qb + (size_t)gr * DIM + h * HEAD_DIM + g * 8);
    }
    __syncthreads();
    short8 qf[8];
#pragma unroll
    for (int ds = 0; ds < 8; ++ds)
        qf[ds] = *(const short8*)&KV[(w * 32 + llo) * 128 + ds * 16 + lhi * 8];
    __syncthreads();

    const int myq = q0 + w * 32 + llo;
    const int mylimit = (myq < FRAME_LEN) ? FRAME_LEN : SEQ_LEN;
    const int wave_lim = (q0 + w * 32 < FRAME_LEN) ? FRAME_LEN : SEQ_LEN;
    const int Lmax = (tile < 6) ? FRAME_LEN : SEQ_LEN;
    const int nch = (Lmax + 63) >> 6;
    const int kc0 = ((split * nch) / nsp) * 64;
    const int kc1 = (((split + 1) * nch) / nsp) * 64;

    float l_run = 0.f;
    f32x16 o[4];
#pragma unroll
    for (int mt = 0; mt < 4; ++mt)
#pragma unroll
        for (int r = 0; r < 16; ++r) o[mt][r] = 0.f;

    int krloc[2], kcol[2], vcol[2], lof[2];
    size_t vrow[2];
#pragma unroll
    for (int s = 0; s < 2; ++s) {
        const int c = (s * 8 + w) * 64 + l;
        const int kr = c >> 4;
        krloc[s] = kr;
        kcol[s] = h * HEAD_DIM + (((c & 15) ^ (kr & 7)) * 8);
        const int d = c >> 3;
        vrow[s] = (size_t)(h * HEAD_DIM + d) * SEQ_LEN;
        vcol[s] = ((c & 7) ^ (d & 7)) * 8;
        lof[s] = (s * 8 + w) * 512;
    }

    auto issue = [&](int kc, int bufoff) {
#pragma unroll
        for (int s = 0; s < 2; ++s) {
            const int gr = min(kc + krloc[s], SEQ_LEN - 1);
            async16(KV + bufoff + lof[s], kb + (size_t)gr * DIM + kcol[s]);
        }
#pragma unroll
        for (int s = 0; s < 2; ++s) {
            const int col = min(kc + vcol[s], SEQ_LEN - 8);
            async16(KV + bufoff + 8192 + lof[s], vt + vrow[s] + col);
        }
    };

    issue(kc0, 0);
    int nb = 0;
    for (int kc = kc0; kc < kc1; kc += 64, nb ^= 1) {
        __syncthreads();
        if (kc + 64 < kc1) issue(kc + 64, (nb ^ 1) * 16384);

        const short* Kb = KV + nb * 16384;
        const short* Vb = Kb + 8192;

        f32x16 st[2];
#pragma unroll
        for (int r = 0; r < 16; ++r) { st[0][r] = 0.f; st[1][r] = 0.f; }
#pragma unroll
        for (int ds = 0; ds < 8; ++ds) {
            const int gd = ds * 2 + lhi;
#pragma unroll
            for (int kt = 0; kt < 2; ++kt) {
                const int krow = kt * 32 + llo;
                short8 kf = *(const short8*)&Kb[krow * 128 + ((gd ^ (krow & 7)) * 8)];
                st[kt] = __builtin_amdgcn_mfma_f32_32x32x16_bf16(kf, qf[ds], st[kt], 0, 0, 0);
            }
        }

        if (kc + 64 > wave_lim) {
#pragma unroll
            for (int kt = 0; kt < 2; ++kt)
#pragma unroll
                for (int r = 0; r < 16; ++r) {
                    const int kg = kc + kt * 32 + (r & 3) + 8 * (r >> 2) + 4 * lhi;
                    if (kg >= mylimit) st[kt][r] = -3.0e38f;
                }
        }

        float rs = 0.f;
        unsigned p16[2][8];
#pragma unroll
        for (int kt = 0; kt < 2; ++kt)
#pragma unroll
            for (int r2 = 0; r2 < 8; ++r2) {
                const float p0 = FEXP2(st[kt][2 * r2] - FMAXC2);
                const float p1 = FEXP2(st[kt][2 * r2 + 1] - FMAXC2);
                rs += p0 + p1;
                p16[kt][r2] = pk2bf(p0, p1);
            }
        l_run += rs;

#pragma unroll
        for (int kblk = 0; kblk < 4; ++kblk) {
            const int t = kblk >> 1;
            const int dk    = ((kblk & 1) * 2 + lhi) * 2;
            const int dsend = ((kblk & 1) * 2 + (1 - lhi)) * 2;
            const unsigned r0 = __shfl_xor(p16[t][dsend], 32);
            const unsigned r1 = __shfl_xor(p16[t][dsend + 1], 32);
            union { unsigned u[4]; short8 s8; } pf;
            if (lhi == 0) { pf.u[0] = p16[t][dk]; pf.u[1] = p16[t][dk + 1]; pf.u[2] = r0; pf.u[3] = r1; }
            else          { pf.u[0] = r0; pf.u[1] = r1; pf.u[2] = p16[t][dk]; pf.u[3] = p16[t][dk + 1]; }
#pragma unroll
            for (int mt = 0; mt < 4; ++mt) {
                const int vd = mt * 32 + llo;
                short8 vf = *(const short8*)&Vb[vd * 64 + (((kblk * 2 + lhi) ^ (vd & 7)) * 8)];
                o[mt] = __builtin_amdgcn_mfma_f32_32x32x16_bf16(vf, pf.s8, o[mt], 0, 0, 0);
            }
        }
    }

    const float l_tot = l_run + __shfl_xor(l_run, 32);
    const int slot_o = bx * HEADS + h;
    const int qloc = w * 32 + llo;
    const float inv = (l_tot > 0.f) ? 1.0f / l_tot : 0.f;
    unsigned short* op = part_o + (size_t)slot_o * (BQ * HEAD_DIM) + qloc * HEAD_DIM + 4 * lhi;
#pragma unroll
    for (int mt = 0; mt < 4; ++mt)
#pragma unroll
        for (int g = 0; g < 4; ++g) {
            uint2 u;
            u.x = pk2bf(o[mt][4 * g + 0] * inv, o[mt][4 * g + 1] * inv);
            u.y = pk2bf(o[mt][4 * g + 2] * inv, o[mt][4 * g + 3] * inv);
            *(uint2*)&op[mt * 32 + 8 * g] = u;
        }
    if (lhi == 0) part_ml[(size_t)slot_o * 256 + qloc] = l_tot;
}

// ---------------------------------------------------------------------------
// Combine pass: weights = l_s (common fixed max) -> attb bf16.
// ---------------------------------------------------------------------------
__global__ __launch_bounds__(256) void attn_combine_kernel(
    const unsigned short* __restrict__ part_o, const float* __restrict__ part_ml,
    unsigned short* __restrict__ attb)
{
    const int h = blockIdx.y;
    const int q = blockIdx.x * 8 + (threadIdx.x >> 5);
    const int dq = (threadIdx.x & 31) * 4;
    const int tile = q >> 8, qloc = q & 255;
    int base_bx, ns;
    if (tile < 6) { base_bx = tile * 2; ns = 2; }
    else { base_bx = 12 + (tile - 6) * 4; ns = 4; }

    float W = 0.f;
    float acc[4] = {0.f, 0.f, 0.f, 0.f};
    for (int s = 0; s < ns; ++s) {
        const int slot = (base_bx + s) * HEADS + h;
        const float w = part_ml[(size_t)slot * 256 + qloc];
        if (w > 0.f) {
            W += w;
            const unsigned short* po = part_o +
                (size_t)slot * (BQ * HEAD_DIM) + qloc * HEAD_DIM + dq;
            uint2 u = *(const uint2*)po;
            acc[0] += w * bf2f((unsigned short)(u.x & 0xffff));
            acc[1] += w * bf2f((unsigned short)(u.x >> 16));
            acc[2] += w * bf2f((unsigned short)(u.y & 0xffff));
            acc[3] += w * bf2f((unsigned short)(u.y >> 16));
        }
    }
    const float inv = 1.0f / W;
    uint2 pk;
    pk.x = pk2bf(acc[0] * inv, acc[1] * inv);
    pk.y = pk2bf(acc[2] * inv, acc[3] * inv);
    *(uint2*)&attb[(size_t)q * DIM + h * HEAD_DIM + dq] = pk;
}

// ---------------------------------------------------------------------------
extern "C" void kernel_launch(void* const* d_in, const int* in_sizes, int n_in,
                              void* d_out, int out_size, void* d_ws, size_t ws_size,
                              hipStream_t stream)
{
    const float* hs    = (const float*)d_in[0];
    const float* cosf  = (const float*)d_in[1];
    const float* sinf  = (const float*)d_in[2];
    const float* w_qkv = (const float*)d_in[3];
    const float* b_qkv = (const float*)d_in[4];
    const float* g_q   = (const float*)d_in[5];
    const float* g_k   = (const float*)d_in[6];
    const float* w_out = (const float*)d_in[7];
    const float* b_out = (const float*)d_in[8];

    // workspace layout, 100,343,808 B total (r11/r12 layout).
    char* base = (char*)d_ws;
    unsigned short* qb     = (unsigned short*)base;                //  9,584,640
    unsigned short* kb     = (unsigned short*)(base + 9584640);    //  9,584,640
    unsigned short* vt     = (unsigned short*)(base + 19169280);   //  9,584,640 (alias hsb)
    unsigned short* hsb    = vt;
    unsigned short* qkvb   = (unsigned short*)(base + 28753920);   // 28,753,920
    unsigned short* part_o = (unsigned short*)(base + 28753920);   // 31,457,280 (alias qkvb)
    float*          part_ml= (float*)(base + 60211200);            //    491,520 (alias qkvb)
    unsigned short* wqkvT  = (unsigned short*)(base + 81469440);   // 14,155,776 (alias attb)
    unsigned short* attb   = wqkvT;
    unsigned short* woutT  = (unsigned short*)(base + 95625216);   //  4,718,592
    float* outp = (float*)d_out;

    // 1) fused prep: hs->bf16 + both weight transposes
    prep_kernel<<<4644, 256, 0, stream>>>(hs, hsb, w_qkv, wqkvT, w_out, woutT);
    // 2) qkvb = hs @ w_qkv + b_qkv (bf16), persistent 2-tile single round
    gemm_qkv_kernel<<<456, 256, 0, stream>>>(hsb, wqkvT, b_qkv, qkvb);
    // 3) fused rmsnorm+rope (q pre-scaled by log2e/sqrt(hd)) + V transpose
    normv_kernel<<<SEQ_LEN + 588, 256, 0, stream>>>(qkvb, g_q, g_k, cosf, sinf, qb, kb, vt);
    // 4) attention pass 1: single uniform round (480 blocks, 60/XCD)
    attn_part_kernel<<<480, 512, 0, stream>>>(qb, kb, vt, part_o, part_ml);
    // 5) combine -> attb bf16 [s][h*128+d]
    attn_combine_kernel<<<dim3(SEQ_LEN / 8, HEADS), 256, 0, stream>>>(part_o, part_ml, attb);
    // 6) out = attb @ w_out + b_out (fp32)
    gemm_out_kernel<<<304, 256, 0, stream>>>(attb, woutT, b_out, outp);
}